// Round 2
// baseline (202.120 us; speedup 1.0000x reference)
//
#include <hip/hip_runtime.h>

// KANLayer as one bf16 GEMM: C[8192][1024] = A[8192][7168] * Bt[1024][7168]^T
// (duplicate spline knots folded; base_weight = plane 0).
// GEMM: 8-phase counted-vmcnt schedule (T1 XCD swizzle + T2 LDS XOR swizzle +
// T3/T4 8-phase counted vmcnt + T5 setprio), BM=256 BN=128 BK=64, 8 waves.

#define IN_F   1024
#define OUT_F  1024
#define K_DIM  (IN_F * 7)   // 7168
#define M_DIM  8192
#define N_DIM  OUT_F
#define NT     (K_DIM / 64) // 112 K-tiles

typedef __attribute__((ext_vector_type(8))) __bf16 bf16x8;
typedef __attribute__((ext_vector_type(4))) float f32x4;
typedef __attribute__((ext_vector_type(4))) unsigned short ushort4v;

__device__ inline unsigned short f2bf(float f) {
    union { float f; unsigned int u; } v; v.f = f;
    unsigned int u = v.u;
    return (unsigned short)((u + 0x7FFFu + ((u >> 16) & 1u)) >> 16);  // RNE
}

// --------------------------------------------------------------------------
// fold_w: spline_weight (dup knots summed) + base_weight -> Bt[N][K] bf16.
// k = plane*1024 + i; plane0 = base_weight, 1 = sum(knots0..3), 2..5 = 4..7,
// 6 = sum(knots8..11).
// --------------------------------------------------------------------------
__global__ void fold_w(const float* __restrict__ sw, const float* __restrict__ bw,
                       unsigned short* __restrict__ Bt) {
    int idx = blockIdx.x * 256 + threadIdx.x;       // o*1024 + i
    int o = idx >> 10, i = idx & 1023;
    const float4* p = reinterpret_cast<const float4*>(sw + (size_t)idx * 12);
    float4 a = p[0];
    float4 b = p[1];
    float4 c = p[2];
    size_t base = (size_t)o * K_DIM + i;
    Bt[base         ] = f2bf(bw[idx]);
    Bt[base + 1*1024] = f2bf(a.x + a.y + a.z + a.w);
    Bt[base + 2*1024] = f2bf(b.x);
    Bt[base + 3*1024] = f2bf(b.y);
    Bt[base + 4*1024] = f2bf(b.z);
    Bt[base + 5*1024] = f2bf(b.w);
    Bt[base + 6*1024] = f2bf(c.x + c.y + c.z + c.w);
}

// --------------------------------------------------------------------------
// expand_x: x -> A[M][K] bf16. Plane 0 = x; planes 1..6 = hat_j(clip(x)),
// hat_j(t) = relu(1 - 2.5*|t - (-1+0.4j)|).
// --------------------------------------------------------------------------
__global__ void expand_x(const float* __restrict__ x, unsigned short* __restrict__ Ax) {
    int idx = blockIdx.x * 256 + threadIdx.x;       // m*256 + i4
    int m = idx >> 8, i4 = idx & 255;
    float4 v = reinterpret_cast<const float4*>(x)[idx];
    float vv[4] = {v.x, v.y, v.z, v.w};
    size_t base = (size_t)m * K_DIM + i4 * 4;

    ushort4v s;
    #pragma unroll
    for (int e = 0; e < 4; ++e) s[e] = f2bf(vv[e]);
    *reinterpret_cast<ushort4v*>(Ax + base) = s;

    float xc[4];
    #pragma unroll
    for (int e = 0; e < 4; ++e) xc[e] = fminf(fmaxf(vv[e], -1.0f), 1.0f);

    #pragma unroll
    for (int j = 0; j < 6; ++j) {
        float t = -1.0f + 0.4f * (float)j;
        #pragma unroll
        for (int e = 0; e < 4; ++e)
            s[e] = f2bf(fmaxf(1.0f - fabsf((xc[e] - t) * 2.5f), 0.0f));
        *reinterpret_cast<ushort4v*>(Ax + base + (size_t)(j + 1) * 1024) = s;
    }
}

// --------------------------------------------------------------------------
// 8-phase GEMM. LDS: As 2x[256][64], Bs 2x[128][64], XOR-swizzled
// (byte ^= (row&7)<<4), staged linearly via global_load_lds with
// pre-swizzled per-lane GLOBAL source (swizzle is an involution on bit 4,
// uniform across each 16B chunk).
//
// Race ledger (phase -> reads / stages; regions disjoint within each phase,
// earlier reads of the staged region are barrier-ordered):
//  ph1 rd buf0 A0,B0   st S(t1,A1->buf1)   [A1(buf1) last read prev ph8]
//  ph2 rd buf0 A0,B1   st S(t1,B1->buf1)   [B1(buf1) last read prev ph8]
//  ph3 rd buf0 A1,B0   st S(t2,A0->buf0)   [A0(buf0) last read ph2]
//  ph4 rd buf0 A1,B1   st S(t2,B0->buf0)   [B0(buf0) last read ph3]  vmcnt(3)
//  ph5 rd buf1 A0,B0   st S(t2,A1->buf0)   [A1(buf0) last read ph4]
//  ph6 rd buf1 A0,B1   st S(t2,B1->buf0)   [B1(buf0) last read ph4]
//  ph7 rd buf1 A1,B0   st S(t3,A0->buf1)   [A0(buf1) last read ph6]
//  ph8 rd buf1 A1,B1   st S(t3,B0->buf1)   [B0(buf1) last read ph7]  vmcnt(3)
// vmcnt(3) at ph4 leaves exactly [S(t2,A0),S(t2,B0)] in flight -> all of t1
// landed before ph5 reads buf1. Symmetric at ph8 for t2 before next ph1.
// --------------------------------------------------------------------------
__global__ __launch_bounds__(512, 2) void gemm8p(
        const unsigned short* __restrict__ Ag,   // [M][K] bf16
        const unsigned short* __restrict__ Bg,   // [N][K] bf16
        float* __restrict__ C) {                 // [M][N] f32
    __shared__ unsigned short As[2][256 * 64];   // 64 KiB
    __shared__ unsigned short Bs[2][128 * 64];   // 32 KiB

    const int tid  = threadIdx.x;
    const int wave = tid >> 6;
    const int lane = tid & 63;
    const int wr   = wave >> 1;   // 0..3 (M)
    const int wc   = wave & 1;    // 0..1 (N)

    // T1: bijective XCD swizzle (nwg = 256, divisible by 8)
    const int orig = blockIdx.x;
    const int wg   = ((orig & 7) << 5) | (orig >> 3);
    const int bx   = wg & 7;      // N tile (BN=128)
    const int by   = wg >> 3;     // M tile (BM=256)

    // staging address precompute (pre-swizzled global source)
    const int arow0 = tid >> 3;                                  // u=0: rows 0..63
    const int arow1 = (512 + tid) >> 3;                          // u=1: rows 64..127
    const int acol0 = ((tid & 7) * 16) ^ ((arow0 & 7) << 4);     // bytes within row
    const int acol1 = ((tid & 7) * 16) ^ ((arow1 & 7) << 4);
    const int brow  = tid >> 3;
    const int bcol  = ((tid & 7) * 16) ^ ((brow & 7) << 4);

#define STAGE_A(BUF, HALF, T) do {                                              \
    int kt_ = ((T) < NT ? (T) : NT - 1) * 64;                                   \
    const unsigned short* g0_ = Ag + (size_t)(by * 256 + (HALF) * 128 + arow0) * K_DIM + kt_ + (acol0 >> 1); \
    const unsigned short* g1_ = Ag + (size_t)(by * 256 + (HALF) * 128 + arow1) * K_DIM + kt_ + (acol1 >> 1); \
    __builtin_amdgcn_global_load_lds((const __attribute__((address_space(1))) void*)g0_, \
        (__attribute__((address_space(3))) void*)(As[BUF] + (HALF) * 8192 + wave * 512), 16, 0, 0); \
    __builtin_amdgcn_global_load_lds((const __attribute__((address_space(1))) void*)g1_, \
        (__attribute__((address_space(3))) void*)(As[BUF] + (HALF) * 8192 + 4096 + wave * 512), 16, 0, 0); \
} while (0)

#define STAGE_B(BUF, HALF, T) do {                                              \
    int kt_ = ((T) < NT ? (T) : NT - 1) * 64;                                   \
    const unsigned short* g0_ = Bg + (size_t)(bx * 128 + (HALF) * 64 + brow) * K_DIM + kt_ + (bcol >> 1); \
    __builtin_amdgcn_global_load_lds((const __attribute__((address_space(1))) void*)g0_, \
        (__attribute__((address_space(3))) void*)(Bs[BUF] + (HALF) * 4096 + wave * 512), 16, 0, 0); \
} while (0)

#define VM3 asm volatile("s_waitcnt vmcnt(3)" ::: "memory")
#define VM_NONE (void)0

#define PHASE(BUF, MH, NH, STAGE, VM) do {                                      \
    bf16x8 af[4], bfr[4];                                                       \
    _Pragma("unroll")                                                           \
    for (int m2 = 0; m2 < 2; ++m2)                                              \
        _Pragma("unroll")                                                       \
        for (int kk = 0; kk < 2; ++kk) {                                        \
            int row = (MH) * 128 + wr * 32 + m2 * 16 + (lane & 15);             \
            int off = ((row << 7) + kk * 64 + (lane >> 4) * 16) ^ ((row & 7) << 4); \
            af[m2 * 2 + kk] = *reinterpret_cast<const bf16x8*>((const char*)As[BUF] + off); \
        }                                                                       \
    _Pragma("unroll")                                                           \
    for (int n2 = 0; n2 < 2; ++n2)                                              \
        _Pragma("unroll")                                                       \
        for (int kk = 0; kk < 2; ++kk) {                                        \
            int row = (NH) * 64 + wc * 32 + n2 * 16 + (lane & 15);              \
            int off = ((row << 7) + kk * 64 + (lane >> 4) * 16) ^ ((row & 7) << 4); \
            bfr[n2 * 2 + kk] = *reinterpret_cast<const bf16x8*>((const char*)Bs[BUF] + off); \
        }                                                                       \
    STAGE;                                                                      \
    VM;                                                                         \
    __builtin_amdgcn_s_barrier();                                               \
    asm volatile("s_waitcnt lgkmcnt(0)");                                       \
    __builtin_amdgcn_s_setprio(1);                                              \
    _Pragma("unroll")                                                           \
    for (int m2 = 0; m2 < 2; ++m2)                                              \
        _Pragma("unroll")                                                       \
        for (int n2 = 0; n2 < 2; ++n2)                                          \
            _Pragma("unroll")                                                   \
            for (int kk = 0; kk < 2; ++kk)                                      \
                acc[(MH) * 2 + m2][(NH) * 2 + n2] =                             \
                    __builtin_amdgcn_mfma_f32_16x16x32_bf16(                    \
                        af[m2 * 2 + kk], bfr[n2 * 2 + kk],                      \
                        acc[(MH) * 2 + m2][(NH) * 2 + n2], 0, 0, 0);            \
    __builtin_amdgcn_s_setprio(0);                                              \
    __builtin_amdgcn_s_barrier();                                               \
} while (0)

    f32x4 acc[4][4];
    const f32x4 zero = {0.f, 0.f, 0.f, 0.f};
    #pragma unroll
    for (int m = 0; m < 4; ++m)
        #pragma unroll
        for (int n = 0; n < 4; ++n) acc[m][n] = zero;

    // prologue: stage t0 fully + t1 A0,B0 ; wait t0 landed (leave 3 in flight)
    STAGE_A(0, 0, 0); STAGE_A(0, 1, 0); STAGE_B(0, 0, 0); STAGE_B(0, 1, 0);
    STAGE_A(1, 0, 1); STAGE_B(1, 0, 1);
    asm volatile("s_waitcnt vmcnt(3)" ::: "memory");
    __builtin_amdgcn_s_barrier();

    for (int i = 0; i < NT / 2; ++i) {
        const int t1 = 2 * i + 1, t2 = 2 * i + 2, t3 = 2 * i + 3;
        PHASE(0, 0, 0, STAGE_A(1, 1, t1), VM_NONE);
        PHASE(0, 0, 1, STAGE_B(1, 1, t1), VM_NONE);
        PHASE(0, 1, 0, STAGE_A(0, 0, t2), VM_NONE);
        PHASE(0, 1, 1, STAGE_B(0, 0, t2), VM3);
        PHASE(1, 0, 0, STAGE_A(0, 1, t2), VM_NONE);
        PHASE(1, 0, 1, STAGE_B(0, 1, t2), VM_NONE);
        PHASE(1, 1, 0, STAGE_A(1, 0, t3), VM_NONE);
        PHASE(1, 1, 1, STAGE_B(1, 0, t3), VM3);
    }

    // epilogue: C/D layout (verified): col = lane&15, row = (lane>>4)*4 + reg
    #pragma unroll
    for (int m = 0; m < 4; ++m) {
        #pragma unroll
        for (int n = 0; n < 4; ++n) {
            const int row = by * 256 + (m >> 1) * 128 + wr * 32 + (m & 1) * 16 + ((lane >> 4) << 2);
            const int col = bx * 128 + (n >> 1) * 64 + wc * 32 + (n & 1) * 16 + (lane & 15);
            #pragma unroll
            for (int r = 0; r < 4; ++r)
                C[(size_t)(row + r) * N_DIM + col] = acc[m][n][r];
        }
    }
#undef STAGE_A
#undef STAGE_B
#undef VM3
#undef VM_NONE
#undef PHASE
}

// --------------------------------------------------------------------------
extern "C" void kernel_launch(void* const* d_in, const int* in_sizes, int n_in,
                              void* d_out, int out_size, void* d_ws, size_t ws_size,
                              hipStream_t stream) {
    const float* x  = (const float*)d_in[0];   // (4,2048,1024) f32
    const float* sw = (const float*)d_in[1];   // (1024,1024,12) f32
    const float* bw = (const float*)d_in[2];   // (1024,1024) f32
    float* out = (float*)d_out;                // (4,2048,1024) f32

    unsigned short* Ax = (unsigned short*)d_ws;                                  // 117.4 MB
    unsigned short* Bt = (unsigned short*)((char*)d_ws + (size_t)M_DIM * K_DIM * 2); // 14.7 MB

    fold_w<<<(OUT_F * IN_F) / 256, 256, 0, stream>>>(sw, bw, Bt);
    expand_x<<<(M_DIM * IN_F / 4) / 256, 256, 0, stream>>>(x, Ax);

    gemm8p<<<(N_DIM / 128) * (M_DIM / 256), 512, 0, stream>>>(Ax, Bt, out);
}